// Round 16
// baseline (211.133 us; speedup 1.0000x reference)
//
#include <hip/hip_runtime.h>

#define I_DIM 2304
#define J_DIM 32
#define D_IN  8
#define E_DIM 16
#define B_DIM 64
#define BJE   (B_DIM * J_DIM * E_DIM)  // 32768
#define NC7   256
#define CH7   (I_DIM / NC7)            // 9
#define TILEW 4096                     // floats per 16KB W tile
#define XROW  (CH7 * D_IN)             // 72 floats of x per local b

typedef const __attribute__((address_space(1))) char* gcp_t;
typedef __attribute__((address_space(3)))       char* lcp_t;

// v16 = v13 data path with 8 b's PER WAVE (vs 4): halves the W LDS-read
// cycles per FLOP — the measured binding floor (LDS is a per-CU shared pipe,
// ~12 cyc/b128; v13's W reads alone = 27.6K cyc/CU/pass). Live regs ~230-255;
// __launch_bounds__(256,1) lifts hipcc's empirical VGPR pool cap (256/waves_req)
// to 256 so nothing spills (v8's 8-b attempt spilled at the 512-thr/128 cap).
// Residency drops to ~1 wave/EU — ILP from 8 interleaved bb-chains replaces TLP.
// grid = 512: chunk = bx&255, qb = bx>>8 (2 b-halves). Sync structure, DMA
// swizzle, FIRST template (poison-safe), reduce kernel: all unchanged from v13.
template <bool FIRST>
__global__ __launch_bounds__(256, 1) void caps_pass_v16(
    const float* __restrict__ x,    // [B, I, 8]
    const float* __restrict__ W,    // [I, J, 8, 16]
    const float* __restrict__ b0,   // [I, J]
    const float* __restrict__ Vacc, // [B, J, 16] (ignored when FIRST)
    float* __restrict__ partial)    // [NC7, B, J, 16]
{
    const int tid   = threadIdx.x;
    const int wv    = __builtin_amdgcn_readfirstlane(tid >> 6);  // 0..3 (SGPR)
    const int lane  = tid & 63;
    const int jj    = lane & 31;
    const int eh    = lane >> 5;
    const int km    = jj & 15;
    const int chunk = blockIdx.x & (NC7 - 1);
    const int qb    = blockIdx.x >> 8;           // 0..1
    const int i0    = chunk * CH7;
    const int bloc0 = wv * 8;                    // local b base (SGPR), 8 per wave
    const int bbase = qb * 32 + bloc0;

    __shared__ float Ws[2][TILEW];        // 32 KB, linear (swizzle, no pad)
    __shared__ float Xall[32 * XROW];     // 9.2 KB: [bl][ii][d], 32 local b
    __shared__ float B0s[CH7 * J_DIM];    // 1.15 KB: [ii][j]

    auto stage = [&](int buf, int itile) {
        const char* wt = (const char*)(W + (size_t)itile * TILEW);
#pragma unroll
        for (int r = 0; r < 4; ++r) {
            const int g    = (wv * 4 + r) * 64 + lane;                  // linear dest unit
            const int srcu = (g & ~31) | ((g & 31) ^ ((g >> 5) & 15));  // swizzled src
            __builtin_amdgcn_global_load_lds(
                (gcp_t)(wt + (size_t)srcu * 16),
                (lcp_t)((char*)&Ws[buf][(wv * 4 + r) * 256]),
                16, 0, 0);
        }
    };

    // ---- prologue staging (drained by the first barrier) ----
    stage(0, i0);
    {   // x rows: 32 local b x 9 ii = 288 rows of 8 floats
        for (int row = tid; row < 32 * CH7; row += 256) {
            const int bl = row / CH7, ii = row - bl * CH7;
            const float* xp = x + ((size_t)(qb * 32 + bl) * I_DIM + i0 + ii) * D_IN;
            const float4 a  = *(const float4*)xp;
            const float4 b4 = *(const float4*)(xp + 4);
            float* dq = &Xall[bl * XROW + ii * 8];
            *(float4*)dq = a; *(float4*)(dq + 4) = b4;
        }
    }
    {   // b0 rows (288 elems)
        B0s[tid] = b0[(i0 + (tid >> 5)) * J_DIM + (tid & 31)];
        if (tid < CH7 * J_DIM - 256)
            B0s[256 + tid] = b0[(i0 + 8) * J_DIM + tid];
    }

    float vacc[8][8];
    if constexpr (!FIRST) {
#pragma unroll
        for (int bb = 0; bb < 8; ++bb) {
            const float* vp = Vacc + ((size_t)((bbase + bb) * J_DIM + jj)) * E_DIM + eh * 8;
            const float4 v0 = *(const float4*)vp;
            const float4 v1 = *(const float4*)(vp + 4);
            vacc[bb][0]=v0.x; vacc[bb][1]=v0.y; vacc[bb][2]=v0.z; vacc[bb][3]=v0.w;
            vacc[bb][4]=v1.x; vacc[bb][5]=v1.y; vacc[bb][6]=v1.z; vacc[bb][7]=v1.w;
        }
    }

    float Sacc[8][8];
#pragma unroll
    for (int bb = 0; bb < 8; ++bb)
#pragma unroll
        for (int e = 0; e < 8; ++e) Sacc[bb][e] = 0.f;

    __syncthreads();   // tile 0 + x + b0 visible

    int cur = 0;
    for (int ii = 0; ii < CH7; ++ii) {
        if (ii + 1 < CH7) stage(cur ^ 1, i0 + ii + 1);   // DMA hides under compute

        const float* wb = &Ws[cur][0];
        const float* xr = &Xall[bloc0 * XROW + ii * 8];

        float uh[8][8];
#pragma unroll
        for (int bb = 0; bb < 8; ++bb)
#pragma unroll
            for (int e = 0; e < 8; ++e) uh[bb][e] = 0.f;

        // ---- d = 0..3 ----
#pragma unroll
        for (int d = 0; d < 4; ++d) {
            const int u0 = (d << 2) | (eh << 1);
            const float4 wlo = *(const float4*)&wb[jj * 128 + (((u0    ) ^ km) << 2)];
            const float4 whi = *(const float4*)&wb[jj * 128 + (((u0 | 1) ^ km) << 2)];
#pragma unroll
            for (int bb = 0; bb < 8; ++bb) {
                const float xv = xr[bb * XROW + d];   // wave-uniform LDS broadcast
                uh[bb][0] = fmaf(xv, wlo.x, uh[bb][0]);
                uh[bb][1] = fmaf(xv, wlo.y, uh[bb][1]);
                uh[bb][2] = fmaf(xv, wlo.z, uh[bb][2]);
                uh[bb][3] = fmaf(xv, wlo.w, uh[bb][3]);
                uh[bb][4] = fmaf(xv, whi.x, uh[bb][4]);
                uh[bb][5] = fmaf(xv, whi.y, uh[bb][5]);
                uh[bb][6] = fmaf(xv, whi.z, uh[bb][6]);
                uh[bb][7] = fmaf(xv, whi.w, uh[bb][7]);
            }
        }
        // ---- d = 4..7 ----
#pragma unroll
        for (int d = 4; d < 8; ++d) {
            const int u0 = (d << 2) | (eh << 1);
            const float4 wlo = *(const float4*)&wb[jj * 128 + (((u0    ) ^ km) << 2)];
            const float4 whi = *(const float4*)&wb[jj * 128 + (((u0 | 1) ^ km) << 2)];
#pragma unroll
            for (int bb = 0; bb < 8; ++bb) {
                const float xv = xr[bb * XROW + d];
                uh[bb][0] = fmaf(xv, wlo.x, uh[bb][0]);
                uh[bb][1] = fmaf(xv, wlo.y, uh[bb][1]);
                uh[bb][2] = fmaf(xv, wlo.z, uh[bb][2]);
                uh[bb][3] = fmaf(xv, wlo.w, uh[bb][3]);
                uh[bb][4] = fmaf(xv, whi.x, uh[bb][4]);
                uh[bb][5] = fmaf(xv, whi.y, uh[bb][5]);
                uh[bb][6] = fmaf(xv, whi.z, uh[bb][6]);
                uh[bb][7] = fmaf(xv, whi.w, uh[bb][7]);
            }
        }

        const float b0v = B0s[ii * J_DIM + jj];
#pragma unroll
        for (int bb = 0; bb < 8; ++bb) {
            float l;
            if constexpr (FIRST) {
                l = b0v;                           // vacc == 0 on pass 0
            } else {
                float l0 = 0.f, l1 = 0.f;
#pragma unroll
                for (int e = 0; e < 8; e += 2) {
                    l0 = fmaf(vacc[bb][e],     uh[bb][e],     l0);
                    l1 = fmaf(vacc[bb][e + 1], uh[bb][e + 1], l1);
                }
                float lg = l0 + l1;
                lg += __shfl_xor(lg, 32);          // other e-half
                l = b0v + lg;
            }

            // softmax over jj, no max-sub (|l| small, fp32-safe; exact-math equal)
            const float p = __expf(l);
            float s = p;
#pragma unroll
            for (int k = 16; k >= 1; k >>= 1) s += __shfl_xor(s, k);
            const float c = p * __builtin_amdgcn_rcpf(s);

#pragma unroll
            for (int e = 0; e < 8; ++e) Sacc[bb][e] = fmaf(c, uh[bb][e], Sacc[bb][e]);
        }

        __syncthreads();   // drains DMA; next tile ready; readers done with cur
        cur ^= 1;
    }

#pragma unroll
    for (int bb = 0; bb < 8; ++bb) {
        float* pp = partial + (size_t)chunk * BJE
                  + ((size_t)((bbase + bb) * J_DIM + jj)) * E_DIM + eh * 8;
        *(float4*)pp       = make_float4(Sacc[bb][0], Sacc[bb][1], Sacc[bb][2], Sacc[bb][3]);
        *(float4*)(pp + 4) = make_float4(Sacc[bb][4], Sacc[bb][5], Sacc[bb][6], Sacc[bb][7]);
    }
}

// Sum partials over chunks (8 independent accumulators), then squash.
// first_it: WRITE Vacc (creates this call's state; no memset needed);
// final_it: write out.
__global__ __launch_bounds__(256) void reduce_squash(
    const float* __restrict__ partial, float* __restrict__ Vacc,
    float* __restrict__ out, const int nc, const int first_it, const int final_it)
{
    const int t = blockIdx.x * blockDim.x + threadIdx.x;  // 0..BJE-1
    float a0=0.f,a1=0.f,a2=0.f,a3=0.f,a4=0.f,a5=0.f,a6=0.f,a7=0.f;
    for (int c = 0; c < nc; c += 8) {
        a0 += partial[(size_t)(c+0) * BJE + t];
        a1 += partial[(size_t)(c+1) * BJE + t];
        a2 += partial[(size_t)(c+2) * BJE + t];
        a3 += partial[(size_t)(c+3) * BJE + t];
        a4 += partial[(size_t)(c+4) * BJE + t];
        a5 += partial[(size_t)(c+5) * BJE + t];
        a6 += partial[(size_t)(c+6) * BJE + t];
        a7 += partial[(size_t)(c+7) * BJE + t];
    }
    const float acc = ((a0+a1)+(a2+a3)) + ((a4+a5)+(a6+a7));

    float s2 = acc * acc;
#pragma unroll
    for (int k = 8; k >= 1; k >>= 1) s2 += __shfl_xor(s2, k);  // reduce over e
    const float scale = s2 / (1.f + s2) * rsqrtf(s2 + 1e-7f);
    const float v = scale * acc;
    if (final_it)      out[t] = v;
    else if (first_it) Vacc[t] = v;
    else               Vacc[t] += v;
}

extern "C" void kernel_launch(void* const* d_in, const int* in_sizes, int n_in,
                              void* d_out, int out_size, void* d_ws, size_t ws_size,
                              hipStream_t stream) {
    const float* x  = (const float*)d_in[0];   // [64,2304,8]
    const float* W  = (const float*)d_in[1];   // [2304,32,8,16]
    const float* b0 = (const float*)d_in[2];   // [2304,32]
    float* out = (float*)d_out;                // [64,32,16]

    // ws layout: partial[256][BJE] (33.5 MB) + Vacc[BJE] (128 KB); ws proven
    // >= 33.7 MB in rounds 3-15. Pass 0 never reads Vacc; reduce_squash writes
    // it fresh each call -> safe under harness ws poisoning.
    float* partial = (float*)d_ws;
    float* Vacc    = partial + (size_t)NC7 * BJE;

    caps_pass_v16<true><<<NC7 * 2, 256, 0, stream>>>(x, W, b0, Vacc, partial);
    reduce_squash<<<BJE / 256, 256, 0, stream>>>(partial, Vacc, out, NC7, 1, 0);

    caps_pass_v16<false><<<NC7 * 2, 256, 0, stream>>>(x, W, b0, Vacc, partial);
    reduce_squash<<<BJE / 256, 256, 0, stream>>>(partial, Vacc, out, NC7, 0, 0);

    caps_pass_v16<false><<<NC7 * 2, 256, 0, stream>>>(x, W, b0, Vacc, partial);
    reduce_squash<<<BJE / 256, 256, 0, stream>>>(partial, Vacc, out, NC7, 0, 1);
}

// Round 17
// 164.168 us; speedup vs baseline: 1.2861x; 1.2861x over previous
//
#include <hip/hip_runtime.h>

#define I_DIM 2304
#define J_DIM 32
#define D_IN  8
#define E_DIM 16
#define B_DIM 64
#define BJE   (B_DIM * J_DIM * E_DIM)  // 32768
#define NC7   256
#define CH7   (I_DIM / NC7)            // 9
#define TILEW 4096                     // floats per 16KB W tile
#define XROW  (CH7 * D_IN)             // 72 floats of x per local b

typedef const __attribute__((address_space(1))) char* gcp_t;
typedef __attribute__((address_space(3)))       char* lcp_t;

// v17 = v14's 8-deep-batched W reads at __launch_bounds__(256,2).
// hipcc VGPR-cap model (measured r12/r13/r16): cap = 256/min_waves -> (256,3)=85
// forced the v14 batch to be re-sunk (VGPR stayed 84, null result). (256,2)=128
// gives the batch room while residency is UNCHANGED (LDS 38.9KB -> 4 blocks/CU
// = 16 waves/CU; VGPR<=128 also allows 16). FIRST template: pass 0 never reads
// Vacc (poison-safe). Source-XOR-swizzled global_load_lds W staging; grid 1024.
template <bool FIRST>
__global__ __launch_bounds__(256, 2) void caps_pass_v17(
    const float* __restrict__ x,    // [B, I, 8]
    const float* __restrict__ W,    // [I, J, 8, 16]
    const float* __restrict__ b0,   // [I, J]
    const float* __restrict__ Vacc, // [B, J, 16] (ignored when FIRST)
    float* __restrict__ partial)    // [NC7, B, J, 16]
{
    const int tid   = threadIdx.x;
    const int wv    = __builtin_amdgcn_readfirstlane(tid >> 6);  // 0..3 (SGPR)
    const int lane  = tid & 63;
    const int jj    = lane & 31;
    const int eh    = lane >> 5;
    const int km    = jj & 15;
    const int chunk = blockIdx.x & (NC7 - 1);
    const int qb    = blockIdx.x >> 8;
    const int i0    = chunk * CH7;
    const int bloc0 = wv * 4;           // local b base (SGPR)
    const int bbase = qb * 16 + bloc0;

    __shared__ float Ws[2][TILEW];        // 32 KB, linear (swizzle, no pad)
    __shared__ float Xall[16 * XROW];     // 4.6 KB: [bl][ii][d]
    __shared__ float B0s[CH7 * J_DIM];    // 1.15 KB: [ii][j]

    auto stage = [&](int buf, int itile) {
        const char* wt = (const char*)(W + (size_t)itile * TILEW);
#pragma unroll
        for (int r = 0; r < 4; ++r) {
            const int g    = (wv * 4 + r) * 64 + lane;                  // linear dest unit
            const int srcu = (g & ~31) | ((g & 31) ^ ((g >> 5) & 15));  // swizzled src
            __builtin_amdgcn_global_load_lds(
                (gcp_t)(wt + (size_t)srcu * 16),
                (lcp_t)((char*)&Ws[buf][(wv * 4 + r) * 256]),
                16, 0, 0);
        }
    };

    // ---- prologue staging (drained by the first barrier) ----
    stage(0, i0);
    if (tid < 16 * CH7) {                       // x rows: bl = tid/9, ii = tid%9
        const int bl = tid / CH7, ii = tid - bl * CH7;
        const float* xp = x + ((size_t)(qb * 16 + bl) * I_DIM + i0 + ii) * D_IN;
        const float4 a  = *(const float4*)xp;
        const float4 b4 = *(const float4*)(xp + 4);
        float* dq = &Xall[bl * XROW + ii * 8];
        *(float4*)dq = a; *(float4*)(dq + 4) = b4;
    }
    {                                           // b0 rows (288 elems)
        B0s[tid] = b0[(i0 + (tid >> 5)) * J_DIM + (tid & 31)];
        if (tid < CH7 * J_DIM - 256)
            B0s[256 + tid] = b0[(i0 + 8) * J_DIM + tid];
    }

    float vacc[4][8];
    if constexpr (!FIRST) {
#pragma unroll
        for (int bb = 0; bb < 4; ++bb) {
            const float* vp = Vacc + ((size_t)((bbase + bb) * J_DIM + jj)) * E_DIM + eh * 8;
            const float4 v0 = *(const float4*)vp;
            const float4 v1 = *(const float4*)(vp + 4);
            vacc[bb][0]=v0.x; vacc[bb][1]=v0.y; vacc[bb][2]=v0.z; vacc[bb][3]=v0.w;
            vacc[bb][4]=v1.x; vacc[bb][5]=v1.y; vacc[bb][6]=v1.z; vacc[bb][7]=v1.w;
        }
    }

    float Sacc[4][8];
#pragma unroll
    for (int bb = 0; bb < 4; ++bb)
#pragma unroll
        for (int e = 0; e < 8; ++e) Sacc[bb][e] = 0.f;

    __syncthreads();   // tile 0 + x + b0 visible

    int cur = 0;
    for (int ii = 0; ii < CH7; ++ii) {
        if (ii + 1 < CH7) stage(cur ^ 1, i0 + ii + 1);   // DMA hides under compute

        const float* wb = &Ws[cur][0];
        const float* xr = &Xall[bloc0 * XROW + ii * 8];

        float uh[4][8];
#pragma unroll
        for (int bb = 0; bb < 4; ++bb)
#pragma unroll
            for (int e = 0; e < 8; ++e) uh[bb][e] = 0.f;

        // ================= group A: d = 0..3 =================
        {
            // batch-issue all 8 W reads (8-deep LDS queue; one latency exposure)
            float4 w[8];
#pragma unroll
            for (int d = 0; d < 4; ++d) {
                const int u0 = (d << 2) | (eh << 1);
                w[2*d]   = *(const float4*)&wb[jj * 128 + (((u0    ) ^ km) << 2)];
                w[2*d+1] = *(const float4*)&wb[jj * 128 + (((u0 | 1) ^ km) << 2)];
            }
            float xq[4][4];
#pragma unroll
            for (int bb = 0; bb < 4; ++bb) {
                const float4 t = *(const float4*)(xr + bb * XROW);
                xq[bb][0]=t.x; xq[bb][1]=t.y; xq[bb][2]=t.z; xq[bb][3]=t.w;
            }
#pragma unroll
            for (int d = 0; d < 4; ++d) {
                const float4 wlo = w[2*d], whi = w[2*d+1];
#pragma unroll
                for (int bb = 0; bb < 4; ++bb) {
                    const float xv = xq[bb][d];
                    uh[bb][0] = fmaf(xv, wlo.x, uh[bb][0]);
                    uh[bb][1] = fmaf(xv, wlo.y, uh[bb][1]);
                    uh[bb][2] = fmaf(xv, wlo.z, uh[bb][2]);
                    uh[bb][3] = fmaf(xv, wlo.w, uh[bb][3]);
                    uh[bb][4] = fmaf(xv, whi.x, uh[bb][4]);
                    uh[bb][5] = fmaf(xv, whi.y, uh[bb][5]);
                    uh[bb][6] = fmaf(xv, whi.z, uh[bb][6]);
                    uh[bb][7] = fmaf(xv, whi.w, uh[bb][7]);
                }
            }
        }
        // ================= group B: d = 4..7 =================
        {
            float4 w[8];
#pragma unroll
            for (int d = 4; d < 8; ++d) {
                const int u0 = (d << 2) | (eh << 1);
                w[2*(d-4)]   = *(const float4*)&wb[jj * 128 + (((u0    ) ^ km) << 2)];
                w[2*(d-4)+1] = *(const float4*)&wb[jj * 128 + (((u0 | 1) ^ km) << 2)];
            }
            float xq[4][4];
#pragma unroll
            for (int bb = 0; bb < 4; ++bb) {
                const float4 t = *(const float4*)(xr + bb * XROW + 4);
                xq[bb][0]=t.x; xq[bb][1]=t.y; xq[bb][2]=t.z; xq[bb][3]=t.w;
            }
#pragma unroll
            for (int d = 0; d < 4; ++d) {
                const float4 wlo = w[2*d], whi = w[2*d+1];
#pragma unroll
                for (int bb = 0; bb < 4; ++bb) {
                    const float xv = xq[bb][d];
                    uh[bb][0] = fmaf(xv, wlo.x, uh[bb][0]);
                    uh[bb][1] = fmaf(xv, wlo.y, uh[bb][1]);
                    uh[bb][2] = fmaf(xv, wlo.z, uh[bb][2]);
                    uh[bb][3] = fmaf(xv, wlo.w, uh[bb][3]);
                    uh[bb][4] = fmaf(xv, whi.x, uh[bb][4]);
                    uh[bb][5] = fmaf(xv, whi.y, uh[bb][5]);
                    uh[bb][6] = fmaf(xv, whi.z, uh[bb][6]);
                    uh[bb][7] = fmaf(xv, whi.w, uh[bb][7]);
                }
            }
        }

        const float b0v = B0s[ii * J_DIM + jj];
#pragma unroll
        for (int bb = 0; bb < 4; ++bb) {
            float l;
            if constexpr (FIRST) {
                l = b0v;                           // vacc == 0 on pass 0
            } else {
                float l0 = 0.f, l1 = 0.f;
#pragma unroll
                for (int e = 0; e < 8; e += 2) {
                    l0 = fmaf(vacc[bb][e],     uh[bb][e],     l0);
                    l1 = fmaf(vacc[bb][e + 1], uh[bb][e + 1], l1);
                }
                float lg = l0 + l1;
                lg += __shfl_xor(lg, 32);          // other e-half
                l = b0v + lg;
            }

            // softmax over jj, no max-sub (|l| small, fp32-safe; exact-math equal)
            const float p = __expf(l);
            float s = p;
#pragma unroll
            for (int k = 16; k >= 1; k >>= 1) s += __shfl_xor(s, k);
            const float c = p * __builtin_amdgcn_rcpf(s);

#pragma unroll
            for (int e = 0; e < 8; ++e) Sacc[bb][e] = fmaf(c, uh[bb][e], Sacc[bb][e]);
        }

        __syncthreads();   // drains DMA; next tile ready; readers done with cur
        cur ^= 1;
    }

#pragma unroll
    for (int bb = 0; bb < 4; ++bb) {
        float* pp = partial + (size_t)chunk * BJE
                  + ((size_t)((bbase + bb) * J_DIM + jj)) * E_DIM + eh * 8;
        *(float4*)pp       = make_float4(Sacc[bb][0], Sacc[bb][1], Sacc[bb][2], Sacc[bb][3]);
        *(float4*)(pp + 4) = make_float4(Sacc[bb][4], Sacc[bb][5], Sacc[bb][6], Sacc[bb][7]);
    }
}

// Sum partials over chunks (8 independent accumulators), then squash.
// first_it: WRITE Vacc (creates this call's state; no memset needed);
// final_it: write out.
__global__ __launch_bounds__(256) void reduce_squash(
    const float* __restrict__ partial, float* __restrict__ Vacc,
    float* __restrict__ out, const int nc, const int first_it, const int final_it)
{
    const int t = blockIdx.x * blockDim.x + threadIdx.x;  // 0..BJE-1
    float a0=0.f,a1=0.f,a2=0.f,a3=0.f,a4=0.f,a5=0.f,a6=0.f,a7=0.f;
    for (int c = 0; c < nc; c += 8) {
        a0 += partial[(size_t)(c+0) * BJE + t];
        a1 += partial[(size_t)(c+1) * BJE + t];
        a2 += partial[(size_t)(c+2) * BJE + t];
        a3 += partial[(size_t)(c+3) * BJE + t];
        a4 += partial[(size_t)(c+4) * BJE + t];
        a5 += partial[(size_t)(c+5) * BJE + t];
        a6 += partial[(size_t)(c+6) * BJE + t];
        a7 += partial[(size_t)(c+7) * BJE + t];
    }
    const float acc = ((a0+a1)+(a2+a3)) + ((a4+a5)+(a6+a7));

    float s2 = acc * acc;
#pragma unroll
    for (int k = 8; k >= 1; k >>= 1) s2 += __shfl_xor(s2, k);  // reduce over e
    const float scale = s2 / (1.f + s2) * rsqrtf(s2 + 1e-7f);
    const float v = scale * acc;
    if (final_it)      out[t] = v;
    else if (first_it) Vacc[t] = v;
    else               Vacc[t] += v;
}

extern "C" void kernel_launch(void* const* d_in, const int* in_sizes, int n_in,
                              void* d_out, int out_size, void* d_ws, size_t ws_size,
                              hipStream_t stream) {
    const float* x  = (const float*)d_in[0];   // [64,2304,8]
    const float* W  = (const float*)d_in[1];   // [2304,32,8,16]
    const float* b0 = (const float*)d_in[2];   // [2304,32]
    float* out = (float*)d_out;                // [64,32,16]

    // ws layout: partial[256][BJE] (33.5 MB) + Vacc[BJE] (128 KB); ws proven
    // >= 33.7 MB in rounds 3-16. Pass 0 never reads Vacc; reduce_squash writes
    // it fresh each call -> safe under harness ws poisoning.
    float* partial = (float*)d_ws;
    float* Vacc    = partial + (size_t)NC7 * BJE;

    caps_pass_v17<true><<<NC7 * 4, 256, 0, stream>>>(x, W, b0, Vacc, partial);
    reduce_squash<<<BJE / 256, 256, 0, stream>>>(partial, Vacc, out, NC7, 1, 0);

    caps_pass_v17<false><<<NC7 * 4, 256, 0, stream>>>(x, W, b0, Vacc, partial);
    reduce_squash<<<BJE / 256, 256, 0, stream>>>(partial, Vacc, out, NC7, 0, 0);

    caps_pass_v17<false><<<NC7 * 4, 256, 0, stream>>>(x, W, b0, Vacc, partial);
    reduce_squash<<<BJE / 256, 256, 0, stream>>>(partial, Vacc, out, NC7, 0, 1);
}

// Round 18
// 162.516 us; speedup vs baseline: 1.2991x; 1.0102x over previous
//
#include <hip/hip_runtime.h>

#define I_DIM 2304
#define J_DIM 32
#define D_IN  8
#define E_DIM 16
#define B_DIM 64
#define BJE   (B_DIM * J_DIM * E_DIM)  // 32768
#define NC7   256
#define CH7   (I_DIM / NC7)            // 9
#define TILEW 4096                     // floats per 16KB W tile

typedef const __attribute__((address_space(1))) char* gcp_t;
typedef __attribute__((address_space(3)))       char* lcp_t;

// s += permuted(s) via DPP (VALU pipe, not LDS). ctrl must be a literal.
// quad_perm[1,0,3,2]=0xB1 (xor1), quad_perm[2,3,0,1]=0x4E (xor2),
// row_ror:4=0x124, row_ror:8=0x128 (rotation butterflies are sum-correct).
#define DPP_ADD(s, ctrl) ((s) + __int_as_float(__builtin_amdgcn_update_dpp( \
    0, __float_as_int(s), (ctrl), 0xF, 0xF, true)))

// v18 = v17 with the two dominant LDS-pipe consumers removed:
//  (1) x reads: LDS -> global VMEM (uniform addr derived from NON-readfirstlane
//      tid>>6 so hipcc emits vector loads, not the v6 s_load trap). Xall gone.
//  (2) softmax sum: masks 1,2,4,8 via VALU DPP; only xor16 (+logit xor32) stay
//      on the LDS pipe. 6 -> 2 LDS ops per bb per iter.
// Measured LDS-pipe model: was ~25.7us/CU/pass of 42.5 wall; now ~14.3.
// Everything else = v17: (256,2) cap 128 (VGPR 124, no spill), batched W reads,
// source-XOR-swizzled global_load_lds, FIRST template (poison-safe), grid 1024.
template <bool FIRST>
__global__ __launch_bounds__(256, 2) void caps_pass_v18(
    const float* __restrict__ x,    // [B, I, 8]
    const float* __restrict__ W,    // [I, J, 8, 16]
    const float* __restrict__ b0,   // [I, J]
    const float* __restrict__ Vacc, // [B, J, 16] (ignored when FIRST)
    float* __restrict__ partial)    // [NC7, B, J, 16]
{
    const int tid   = threadIdx.x;
    const int wv    = __builtin_amdgcn_readfirstlane(tid >> 6);  // SGPR (staging)
    const int wvx   = tid >> 6;         // NOT readfirstlane: keeps x addr in VGPR
    const int lane  = tid & 63;
    const int jj    = lane & 31;
    const int eh    = lane >> 5;
    const int km    = jj & 15;
    const int chunk = blockIdx.x & (NC7 - 1);
    const int qb    = blockIdx.x >> 8;
    const int i0    = chunk * CH7;
    const int bloc0 = wv * 4;           // local b base (SGPR)
    const int bbase = qb * 16 + bloc0;
    const int bxb   = qb * 16 + wvx * 4; // b base for x addressing (VGPR-typed)

    __shared__ float Ws[2][TILEW];        // 32 KB, linear (swizzle, no pad)
    __shared__ float B0s[CH7 * J_DIM];    // 1.15 KB: [ii][j]

    auto stage = [&](int buf, int itile) {
        const char* wt = (const char*)(W + (size_t)itile * TILEW);
#pragma unroll
        for (int r = 0; r < 4; ++r) {
            const int g    = (wv * 4 + r) * 64 + lane;                  // linear dest unit
            const int srcu = (g & ~31) | ((g & 31) ^ ((g >> 5) & 15));  // swizzled src
            __builtin_amdgcn_global_load_lds(
                (gcp_t)(wt + (size_t)srcu * 16),
                (lcp_t)((char*)&Ws[buf][(wv * 4 + r) * 256]),
                16, 0, 0);
        }
    };

    // ---- prologue staging (drained by the first barrier) ----
    stage(0, i0);
    {                                           // b0 rows (288 elems)
        B0s[tid] = b0[(i0 + (tid >> 5)) * J_DIM + (tid & 31)];
        if (tid < CH7 * J_DIM - 256)
            B0s[256 + tid] = b0[(i0 + 8) * J_DIM + tid];
    }

    float vacc[4][8];
    if constexpr (!FIRST) {
#pragma unroll
        for (int bb = 0; bb < 4; ++bb) {
            const float* vp = Vacc + ((size_t)((bbase + bb) * J_DIM + jj)) * E_DIM + eh * 8;
            const float4 v0 = *(const float4*)vp;
            const float4 v1 = *(const float4*)(vp + 4);
            vacc[bb][0]=v0.x; vacc[bb][1]=v0.y; vacc[bb][2]=v0.z; vacc[bb][3]=v0.w;
            vacc[bb][4]=v1.x; vacc[bb][5]=v1.y; vacc[bb][6]=v1.z; vacc[bb][7]=v1.w;
        }
    }

    float Sacc[4][8];
#pragma unroll
    for (int bb = 0; bb < 4; ++bb)
#pragma unroll
        for (int e = 0; e < 8; ++e) Sacc[bb][e] = 0.f;

    __syncthreads();   // tile 0 + b0 visible

    int cur = 0;
    for (int ii = 0; ii < CH7; ++ii) {
        const int i = i0 + ii;
        if (ii + 1 < CH7) stage(cur ^ 1, i + 1);   // DMA hides under compute

        const float* wb = &Ws[cur][0];

        float uh[4][8];
#pragma unroll
        for (int bb = 0; bb < 4; ++bb)
#pragma unroll
            for (int e = 0; e < 8; ++e) uh[bb][e] = 0.f;

        // ================= group A: d = 0..3 =================
        {
            float xq[4][4];
#pragma unroll
            for (int bb = 0; bb < 4; ++bb) {   // uniform VMEM loads (L1 broadcast)
                const float4 t = *(const float4*)(x + ((size_t)(bxb + bb) * I_DIM + i) * D_IN);
                xq[bb][0]=t.x; xq[bb][1]=t.y; xq[bb][2]=t.z; xq[bb][3]=t.w;
            }
            float4 w[8];
#pragma unroll
            for (int d = 0; d < 4; ++d) {
                const int u0 = (d << 2) | (eh << 1);
                w[2*d]   = *(const float4*)&wb[jj * 128 + (((u0    ) ^ km) << 2)];
                w[2*d+1] = *(const float4*)&wb[jj * 128 + (((u0 | 1) ^ km) << 2)];
            }
#pragma unroll
            for (int d = 0; d < 4; ++d) {
                const float4 wlo = w[2*d], whi = w[2*d+1];
#pragma unroll
                for (int bb = 0; bb < 4; ++bb) {
                    const float xv = xq[bb][d];
                    uh[bb][0] = fmaf(xv, wlo.x, uh[bb][0]);
                    uh[bb][1] = fmaf(xv, wlo.y, uh[bb][1]);
                    uh[bb][2] = fmaf(xv, wlo.z, uh[bb][2]);
                    uh[bb][3] = fmaf(xv, wlo.w, uh[bb][3]);
                    uh[bb][4] = fmaf(xv, whi.x, uh[bb][4]);
                    uh[bb][5] = fmaf(xv, whi.y, uh[bb][5]);
                    uh[bb][6] = fmaf(xv, whi.z, uh[bb][6]);
                    uh[bb][7] = fmaf(xv, whi.w, uh[bb][7]);
                }
            }
        }
        // ================= group B: d = 4..7 =================
        {
            float xq[4][4];
#pragma unroll
            for (int bb = 0; bb < 4; ++bb) {
                const float4 t = *(const float4*)(x + ((size_t)(bxb + bb) * I_DIM + i) * D_IN + 4);
                xq[bb][0]=t.x; xq[bb][1]=t.y; xq[bb][2]=t.z; xq[bb][3]=t.w;
            }
            float4 w[8];
#pragma unroll
            for (int d = 4; d < 8; ++d) {
                const int u0 = (d << 2) | (eh << 1);
                w[2*(d-4)]   = *(const float4*)&wb[jj * 128 + (((u0    ) ^ km) << 2)];
                w[2*(d-4)+1] = *(const float4*)&wb[jj * 128 + (((u0 | 1) ^ km) << 2)];
            }
#pragma unroll
            for (int d = 0; d < 4; ++d) {
                const float4 wlo = w[2*d], whi = w[2*d+1];
#pragma unroll
                for (int bb = 0; bb < 4; ++bb) {
                    const float xv = xq[bb][d];
                    uh[bb][0] = fmaf(xv, wlo.x, uh[bb][0]);
                    uh[bb][1] = fmaf(xv, wlo.y, uh[bb][1]);
                    uh[bb][2] = fmaf(xv, wlo.z, uh[bb][2]);
                    uh[bb][3] = fmaf(xv, wlo.w, uh[bb][3]);
                    uh[bb][4] = fmaf(xv, whi.x, uh[bb][4]);
                    uh[bb][5] = fmaf(xv, whi.y, uh[bb][5]);
                    uh[bb][6] = fmaf(xv, whi.z, uh[bb][6]);
                    uh[bb][7] = fmaf(xv, whi.w, uh[bb][7]);
                }
            }
        }

        const float b0v = B0s[ii * J_DIM + jj];
#pragma unroll
        for (int bb = 0; bb < 4; ++bb) {
            float l;
            if constexpr (FIRST) {
                l = b0v;                           // vacc == 0 on pass 0
            } else {
                float l0 = 0.f, l1 = 0.f;
#pragma unroll
                for (int e = 0; e < 8; e += 2) {
                    l0 = fmaf(vacc[bb][e],     uh[bb][e],     l0);
                    l1 = fmaf(vacc[bb][e + 1], uh[bb][e + 1], l1);
                }
                float lg = l0 + l1;
                lg += __shfl_xor(lg, 32);          // other e-half (LDS, kept)
                l = b0v + lg;
            }

            // softmax over jj: within-16 sum on the VALU (DPP), xor16 on LDS.
            const float p = __expf(l);
            float s = p;
            s = DPP_ADD(s, 0xB1);    // xor1  (quad_perm [1,0,3,2])
            s = DPP_ADD(s, 0x4E);    // xor2  (quad_perm [2,3,0,1])
            s = DPP_ADD(s, 0x124);   // ror4  within 16-row
            s = DPP_ADD(s, 0x128);   // ror8  -> row-16 sum
            s += __shfl_xor(s, 16);  // cross 16-row -> 32-lane sum
            const float c = p * __builtin_amdgcn_rcpf(s);

#pragma unroll
            for (int e = 0; e < 8; ++e) Sacc[bb][e] = fmaf(c, uh[bb][e], Sacc[bb][e]);
        }

        __syncthreads();   // drains DMA; next tile ready; readers done with cur
        cur ^= 1;
    }

#pragma unroll
    for (int bb = 0; bb < 4; ++bb) {
        float* pp = partial + (size_t)chunk * BJE
                  + ((size_t)((bbase + bb) * J_DIM + jj)) * E_DIM + eh * 8;
        *(float4*)pp       = make_float4(Sacc[bb][0], Sacc[bb][1], Sacc[bb][2], Sacc[bb][3]);
        *(float4*)(pp + 4) = make_float4(Sacc[bb][4], Sacc[bb][5], Sacc[bb][6], Sacc[bb][7]);
    }
}

// Sum partials over chunks (8 independent accumulators), then squash.
// first_it: WRITE Vacc (creates this call's state; no memset needed);
// final_it: write out.
__global__ __launch_bounds__(256) void reduce_squash(
    const float* __restrict__ partial, float* __restrict__ Vacc,
    float* __restrict__ out, const int nc, const int first_it, const int final_it)
{
    const int t = blockIdx.x * blockDim.x + threadIdx.x;  // 0..BJE-1
    float a0=0.f,a1=0.f,a2=0.f,a3=0.f,a4=0.f,a5=0.f,a6=0.f,a7=0.f;
    for (int c = 0; c < nc; c += 8) {
        a0 += partial[(size_t)(c+0) * BJE + t];
        a1 += partial[(size_t)(c+1) * BJE + t];
        a2 += partial[(size_t)(c+2) * BJE + t];
        a3 += partial[(size_t)(c+3) * BJE + t];
        a4 += partial[(size_t)(c+4) * BJE + t];
        a5 += partial[(size_t)(c+5) * BJE + t];
        a6 += partial[(size_t)(c+6) * BJE + t];
        a7 += partial[(size_t)(c+7) * BJE + t];
    }
    const float acc = ((a0+a1)+(a2+a3)) + ((a4+a5)+(a6+a7));

    float s2 = acc * acc;
#pragma unroll
    for (int k = 8; k >= 1; k >>= 1) s2 += __shfl_xor(s2, k);  // reduce over e
    const float scale = s2 / (1.f + s2) * rsqrtf(s2 + 1e-7f);
    const float v = scale * acc;
    if (final_it)      out[t] = v;
    else if (first_it) Vacc[t] = v;
    else               Vacc[t] += v;
}

extern "C" void kernel_launch(void* const* d_in, const int* in_sizes, int n_in,
                              void* d_out, int out_size, void* d_ws, size_t ws_size,
                              hipStream_t stream) {
    const float* x  = (const float*)d_in[0];   // [64,2304,8]
    const float* W  = (const float*)d_in[1];   // [2304,32,8,16]
    const float* b0 = (const float*)d_in[2];   // [2304,32]
    float* out = (float*)d_out;                // [64,32,16]

    // ws layout: partial[256][BJE] (33.5 MB) + Vacc[BJE] (128 KB); ws proven
    // >= 33.7 MB in rounds 3-17. Pass 0 never reads Vacc; reduce_squash writes
    // it fresh each call -> safe under harness ws poisoning.
    float* partial = (float*)d_ws;
    float* Vacc    = partial + (size_t)NC7 * BJE;

    caps_pass_v18<true><<<NC7 * 4, 256, 0, stream>>>(x, W, b0, Vacc, partial);
    reduce_squash<<<BJE / 256, 256, 0, stream>>>(partial, Vacc, out, NC7, 1, 0);

    caps_pass_v18<false><<<NC7 * 4, 256, 0, stream>>>(x, W, b0, Vacc, partial);
    reduce_squash<<<BJE / 256, 256, 0, stream>>>(partial, Vacc, out, NC7, 0, 0);

    caps_pass_v18<false><<<NC7 * 4, 256, 0, stream>>>(x, W, b0, Vacc, partial);
    reduce_squash<<<BJE / 256, 256, 0, stream>>>(partial, Vacc, out, NC7, 0, 1);
}